// Round 4
// baseline (144.153 us; speedup 1.0000x reference)
//
#include <hip/hip_runtime.h>
#include <math.h>

// (B,C,H,W)=(8,512,32,32), L=1024, 32 groups, 8 heads, ch=64
#define BATCH   8
#define CCH     512
#define LL      1024
#define NHEADS  8
#define CHD     64
#define EPSV    1e-5f
#define QSCALE  0.1803368801111204f   // 0.125 / ln(2): folded into q so S is in log2 units

typedef __bf16 bf16_t;
typedef bf16_t bf16x8 __attribute__((ext_vector_type(8)));
typedef bf16_t bf16x4 __attribute__((ext_vector_type(4)));
typedef float  f32x4  __attribute__((ext_vector_type(4)));
typedef short  s16x4  __attribute__((ext_vector_type(4)));

__device__ __forceinline__ bf16_t f2b(float f) {
  unsigned u = __float_as_uint(f);
  u += 0x7fff + ((u >> 16) & 1);               // RNE
  return __builtin_bit_cast(bf16_t, (unsigned short)(u >> 16));
}

__device__ __forceinline__ unsigned pack2(float lo, float hi) {
  unsigned a = (unsigned)__builtin_bit_cast(unsigned short, f2b(lo));
  unsigned b = (unsigned)__builtin_bit_cast(unsigned short, f2b(hi));
  return (b << 16) | a;
}

__device__ __forceinline__ unsigned cvtpk_bf16(float lo, float hi) {
  unsigned r;
  asm("v_cvt_pk_bf16_f32 %0, %1, %2" : "=v"(r) : "v"(lo), "v"(hi));
  return r;
}

__device__ __forceinline__ void gload_lds16(const void* g, void* l) {
  __builtin_amdgcn_global_load_lds(
      (const __attribute__((address_space(1))) void*)g,
      (__attribute__((address_space(3))) void*)l, 16, 0, 0);
}

// ---------------------------------------------------------------------------
// K1: fused prep.  Blocks 0..1023: fp32->bf16 weight convert (qkv_w + proj_w).
// Blocks 1024..1279: GroupNorm stats+normalize+affine+transpose -> xnT bf16.
// ---------------------------------------------------------------------------
__global__ __launch_bounds__(256) void prep_fused(const float* __restrict__ qkvw,
                                                  const float* __restrict__ projw,
                                                  bf16_t* __restrict__ wqb,
                                                  bf16_t* __restrict__ wpb,
                                                  const float* __restrict__ x,
                                                  const float* __restrict__ gsc,
                                                  const float* __restrict__ gbi,
                                                  bf16_t* __restrict__ xnT) {
  int bid = blockIdx.x;
  int tid = threadIdx.x;
  if (bid < 1024) {
    int i = (bid * 256 + tid) * 4;
    const float* src;
    bf16_t* dst;
    int j;
    if (i < 1536 * 512) { src = qkvw; dst = wqb; j = i; }
    else                { src = projw; dst = wpb; j = i - 1536 * 512; }
    float4 v = *(const float4*)(src + j);
    bf16x4 o = {f2b(v.x), f2b(v.y), f2b(v.z), f2b(v.w)};
    *(bf16x4*)(dst + j) = o;
    return;
  }
  int lin = bid - 1024;
  int xcd = lin & 7, slot = lin >> 3;
  int b = slot & 7, jj = slot >> 3;
  int g = xcd * 4 + jj;
  const float4* x4 = (const float4*)(x + ((size_t)(b * 32 + g)) * 16 * LL);

  float s = 0.f, ss = 0.f;
  float4 v[16];
#pragma unroll
  for (int it = 0; it < 16; ++it) {
    float4 f = x4[it * 256 + tid];
    v[it] = f;
    s += f.x + f.y + f.z + f.w;
    ss += f.x * f.x + f.y * f.y + f.z * f.z + f.w * f.w;
  }
#pragma unroll
  for (int m = 1; m < 64; m <<= 1) { s += __shfl_xor(s, m); ss += __shfl_xor(ss, m); }
  __shared__ float rs_[4], rss[4];
  int wv = tid >> 6, ln = tid & 63;
  if (ln == 0) { rs_[wv] = s; rss[wv] = ss; }
  __syncthreads();
  s  = rs_[0] + rs_[1] + rs_[2] + rs_[3];
  ss = rss[0] + rss[1] + rss[2] + rss[3];
  float mean = s * (1.f / 16384.f);
  float var  = ss * (1.f / 16384.f) - mean * mean;
  float rstd = rsqrtf(var + EPSV);

  float sc[16], bi[16];
#pragma unroll
  for (int it = 0; it < 16; ++it) {
    sc[it] = gsc[g * 16 + it] * rstd;
    bi[it] = gbi[g * 16 + it] - mean * sc[it];
  }

#pragma unroll
  for (int j = 0; j < 4; ++j) {
    unsigned w[8];
#pragma unroll
    for (int k = 0; k < 8; ++k) {
      float a0 = (j == 0 ? v[2 * k].x : j == 1 ? v[2 * k].y : j == 2 ? v[2 * k].z : v[2 * k].w);
      float a1 = (j == 0 ? v[2 * k + 1].x : j == 1 ? v[2 * k + 1].y : j == 2 ? v[2 * k + 1].z : v[2 * k + 1].w);
      w[k] = pack2(a0 * sc[2 * k] + bi[2 * k], a1 * sc[2 * k + 1] + bi[2 * k + 1]);
    }
    int l = tid * 4 + j;
    bf16_t* dst = xnT + ((size_t)b * LL + l) * CCH + g * 16;
    *(uint4*)dst = make_uint4(w[0], w[1], w[2], w[3]);
    *(uint4*)(dst + 8) = make_uint4(w[4], w[5], w[6], w[7]);
  }
}

// ---------------------------------------------------------------------------
// K2: qkv GEMM (MFMA).  128x128 block tile, grid (8,12,8)=768 = 3/CU.
// Bs dbuf + counted s_waitcnt vmcnt(4) pipeline (T3/T4).  Wave tile 64x64.
// NEW (this round): v epilogue writes vt in NATURAL column order (the old
// s-permute existed only to match K3's P-through-LDS path, now removed).
// ---------------------------------------------------------------------------
__global__ __launch_bounds__(256, 3) void qkv_mfma(const bf16_t* __restrict__ wq,
                                                   const bf16_t* __restrict__ xnT,
                                                   const float* __restrict__ qkvb,
                                                   bf16_t* __restrict__ qt,
                                                   bf16_t* __restrict__ kt,
                                                   bf16_t* __restrict__ vt) {
  __shared__ bf16_t As[128 * 64];       // single buffer (weights)
  __shared__ bf16_t Bs[2][128 * 64];    // double buffer (activations)
  int tid = threadIdx.x;
  int wave = tid >> 6, lane = tid & 63;
  int lrow = lane & 15, quad = lane >> 4;
  int wm = wave >> 1, wn = wave & 1;
  int b = blockIdx.x;
  int oBase = blockIdx.y * 128, lBase = blockIdx.z * 128;
  int srow = lane >> 3;
  int sgOff = (((lane & 7) ^ srow) << 4);

  // prologue: issue Bs[0] for ktile 0
#pragma unroll
  for (int j = 0; j < 4; ++j) {
    int ci = wave * 4 + j;
    int R = ci * 8 + srow;
    gload_lds16((const char*)(xnT + ((size_t)b * LL + lBase + R) * CCH) + sgOff,
                (char*)&Bs[0][0] + ci * 1024);
  }

  f32x4 acc[4][4] = {};
  for (int ktile = 0; ktile < 8; ++ktile) {
    int cur = ktile & 1;
    int kB = ktile * 64;
    __builtin_amdgcn_sched_barrier(0);
    __builtin_amdgcn_s_barrier();        // all waves done reading As / Bs[cur^1]
    __builtin_amdgcn_sched_barrier(0);
#pragma unroll
    for (int j = 0; j < 4; ++j) {        // As for THIS ktile (single buffer)
      int ci = wave * 4 + j;
      int R = ci * 8 + srow;
      gload_lds16((const char*)(wq + (size_t)(oBase + R) * CCH + kB) + sgOff,
                  (char*)As + ci * 1024);
    }
    if (ktile < 7) {
#pragma unroll
      for (int j = 0; j < 4; ++j) {      // Bs prefetch for NEXT ktile
        int ci = wave * 4 + j;
        int R = ci * 8 + srow;
        gload_lds16((const char*)(xnT + ((size_t)b * LL + lBase + R) * CCH + kB + 64) + sgOff,
                    (char*)&Bs[cur ^ 1][0] + ci * 1024);
      }
      asm volatile("s_waitcnt vmcnt(4)" ::: "memory");  // As_k + Bs_k retired; Bs_{k+1} flies
    } else {
      asm volatile("s_waitcnt vmcnt(0)" ::: "memory");
    }
    __builtin_amdgcn_s_barrier();        // staged data visible to all waves
    __builtin_amdgcn_sched_barrier(0);
    const bf16_t* bsrc = &Bs[cur][0];
#pragma unroll
    for (int kk = 0; kk < 2; ++kk) {
      int g = (kk * 4 + quad) ^ (lrow & 7);
      bf16x8 af[4], bfr[4];
#pragma unroll
      for (int m = 0; m < 4; ++m) {
        int r = wm * 64 + m * 16 + lrow;
        af[m] = *(const bf16x8*)(As + r * 64 + g * 8);
      }
#pragma unroll
      for (int n = 0; n < 4; ++n) {
        int r = wn * 64 + n * 16 + lrow;
        bfr[n] = *(const bf16x8*)(bsrc + r * 64 + g * 8);
      }
#pragma unroll
      for (int m = 0; m < 4; ++m)
#pragma unroll
        for (int n = 0; n < 4; ++n)
          acc[m][n] = __builtin_amdgcn_mfma_f32_16x16x32_bf16(af[m], bfr[n], acc[m][n], 0, 0, 0);
    }
  }

  int oW = oBase + wm * 64;
  int lW = lBase + wn * 64;
  int sec = oW >> 9;                            // wave-uniform
#pragma unroll
  for (int m = 0; m < 4; ++m) {
    int o4 = oW + m * 16 + quad * 4;
    float4 bb4 = *(const float4*)&qkvb[o4];
    int cc = o4 & 511;
    int head = cc >> 6, ch = cc & 63;
    int bh = b * NHEADS + head;
    if (sec == 0) {
#pragma unroll
      for (int n = 0; n < 4; ++n) {
        int l = lW + n * 16 + lrow;
        unsigned d0 = pack2((acc[m][n][0] + bb4.x) * QSCALE,
                            (acc[m][n][1] + bb4.y) * QSCALE);
        unsigned d1 = pack2((acc[m][n][2] + bb4.z) * QSCALE,
                            (acc[m][n][3] + bb4.w) * QSCALE);
        *(uint2*)(qt + ((size_t)bh * LL + l) * CHD + ch) = make_uint2(d0, d1);
      }
    } else if (sec == 1) {
#pragma unroll
      for (int n = 0; n < 4; ++n) {
        int l = lW + n * 16 + lrow;
        unsigned d0 = pack2(acc[m][n][0] + bb4.x, acc[m][n][1] + bb4.y);
        unsigned d1 = pack2(acc[m][n][2] + bb4.z, acc[m][n][3] + bb4.w);
        *(uint2*)(kt + ((size_t)bh * LL + l) * CHD + ch) = make_uint2(d0, d1);
      }
    } else {
      // v: natural layout vt[(bh*CHD + ch)*LL + l]
      float bb[4] = {bb4.x, bb4.y, bb4.z, bb4.w};
#pragma unroll
      for (int i = 0; i < 4; ++i) {
        bf16_t* vrow = vt + ((size_t)bh * CHD + ch + i) * LL;
#pragma unroll
        for (int n = 0; n < 4; ++n)
          vrow[lW + n * 16 + lrow] = f2b(acc[m][n][i] + bb[i]);
      }
    }
  }
}

// ---------------------------------------------------------------------------
// K3: flash attention (MFMA), no-max softmax in log2 units.
// NEW (this round): register-only P path.  QK^T computed SWAPPED
// (mfma(kfrag, qfrag) — per-lane fragment data is identical, so the swap is
// free) producing S^T with col=q=lane&15, row=s=16ss+4quad+i.  That is
// exactly the B-fragment layout of v_mfma_f32_16x16x16_bf16 (k=4*quad+i), so
// PV runs as O^T += mfma_16x16x16(V^T-frag from vbuf, P^T packed in-register
// via v_cvt_pk_bf16_f32).  Removes: P LDS round-trip + lgkmcnt(0) serialize,
// pb (18 KB LDS -> 32 KB total), ones-MFMA (row-sum = per-lane f32 adds + 2
// final shfl_xor), scalar epilogue (now 8 uint2 stores).  Requires vt in
// natural column order (K2 change).  K/V dbuf + XOR-granule swizzle kept.
// ---------------------------------------------------------------------------
__global__ __launch_bounds__(256, 3) void attn_mfma(const bf16_t* __restrict__ qt,
                                                    const bf16_t* __restrict__ kt,
                                                    const bf16_t* __restrict__ vt,
                                                    bf16_t* __restrict__ at) {
  __shared__ bf16_t kbuf[2][64 * 64];
  __shared__ bf16_t vbuf[2][64 * 64];
  int tid = threadIdx.x, wave = tid >> 6, lane = tid & 63;
  int lrow = lane & 15, quad = lane >> 4;
  int bh = blockIdx.x;
  int tW = blockIdx.y * 128 + wave * 32;
  const bf16_t* qb = qt + (size_t)bh * LL * CHD;
  const bf16_t* kb = kt + (size_t)bh * LL * CHD;
  const bf16_t* vb = vt + (size_t)bh * CHD * LL;

  int srow = lane >> 3;
  int sgb = (((lane & 7) ^ srow) << 4);

  bf16x8 qf[2][2];
#pragma unroll
  for (int h = 0; h < 2; ++h) {
    const bf16_t* qp = qb + (size_t)(tW + h * 16 + lrow) * CHD + quad * 8;
    qf[h][0] = *(const bf16x8*)qp;
    qf[h][1] = *(const bf16x8*)(qp + 32);
  }

  f32x4 Oa[2][4] = {};
  float Osum[2] = {0.f, 0.f};

#pragma unroll
  for (int j = 0; j < 2; ++j) {
    int c = wave * 2 + j;
    int R = c * 8 + srow;
    gload_lds16((const char*)(kb + (size_t)R * CHD) + sgb, (char*)&kbuf[0][0] + c * 1024);
    gload_lds16((const char*)(vb + (size_t)R * LL) + sgb, (char*)&vbuf[0][0] + c * 1024);
  }
  __syncthreads();

  int swz0 = (quad ^ (lrow & 7)) * 8;
  int swz1 = ((quad + 4) ^ (lrow & 7)) * 8;

  for (int st = 0; st < 16; ++st) {
    int cur = st & 1;
    if (st < 15) {
      int sBn = (st + 1) * 64;
#pragma unroll
      for (int j = 0; j < 2; ++j) {
        int c = wave * 2 + j;
        int R = c * 8 + srow;
        gload_lds16((const char*)(kb + (size_t)(sBn + R) * CHD) + sgb,
                    (char*)&kbuf[cur ^ 1][0] + c * 1024);
        gload_lds16((const char*)(vb + (size_t)R * LL + sBn) + sgb,
                    (char*)&vbuf[cur ^ 1][0] + c * 1024);
      }
    }
    const bf16_t* kbase = &kbuf[cur][0];
    const bf16_t* vbase = &vbuf[cur][0];

    // S^T = K · Q^T per ss-subtile: row s, col q
    f32x4 S[2][4];
    __builtin_amdgcn_s_setprio(1);
#pragma unroll
    for (int ss = 0; ss < 4; ++ss) {
      int s = ss * 16 + lrow;
      bf16x8 k0 = *(const bf16x8*)(kbase + s * 64 + swz0);
      bf16x8 k1 = *(const bf16x8*)(kbase + s * 64 + swz1);
#pragma unroll
      for (int h = 0; h < 2; ++h) {
        f32x4 z = {0.f, 0.f, 0.f, 0.f};
        z = __builtin_amdgcn_mfma_f32_16x16x32_bf16(k0, qf[h][0], z, 0, 0, 0);
        S[h][ss] = __builtin_amdgcn_mfma_f32_16x16x32_bf16(k1, qf[h][1], z, 0, 0, 0);
      }
    }
    __builtin_amdgcn_s_setprio(0);

    // exp2 + in-register pack to PV B-fragments; accumulate per-lane row sums
    s16x4 pf[2][4];
#pragma unroll
    for (int h = 0; h < 2; ++h)
#pragma unroll
      for (int ss = 0; ss < 4; ++ss) {
        float p0 = __builtin_amdgcn_exp2f(S[h][ss][0]);
        float p1 = __builtin_amdgcn_exp2f(S[h][ss][1]);
        float p2 = __builtin_amdgcn_exp2f(S[h][ss][2]);
        float p3 = __builtin_amdgcn_exp2f(S[h][ss][3]);
        Osum[h] += (p0 + p1) + (p2 + p3);
        unsigned u0 = cvtpk_bf16(p0, p1);
        unsigned u1 = cvtpk_bf16(p2, p3);
        unsigned long long uu = ((unsigned long long)u1 << 32) | u0;
        pf[h][ss] = __builtin_bit_cast(s16x4, uu);
      }

    // O^T += V^T · P^T  (16x16x16 MFMA, K=16 per ss)
    __builtin_amdgcn_s_setprio(1);
#pragma unroll
    for (int n = 0; n < 4; ++n) {
      int rv = n * 16 + lrow;                    // d-row in vbuf
#pragma unroll
      for (int ss = 0; ss < 4; ++ss) {
        int slot = ((ss << 1) + (quad >> 1)) ^ (lrow & 7);
        s16x4 vfrag = *(const s16x4*)(vbase + rv * 64 + slot * 8 + (quad & 1) * 4);
#pragma unroll
        for (int h = 0; h < 2; ++h)
          Oa[h][n] = __builtin_amdgcn_mfma_f32_16x16x16bf16_1k(vfrag, pf[h][ss], Oa[h][n], 0, 0, 0);
      }
    }
    __builtin_amdgcn_s_setprio(0);

    __syncthreads();
  }

  // reduce row-sums across quads (each lane then holds full sum for its q)
#pragma unroll
  for (int h = 0; h < 2; ++h) {
    Osum[h] += __shfl_xor(Osum[h], 16);
    Osum[h] += __shfl_xor(Osum[h], 32);
  }

  bf16_t* ab = at + (size_t)bh * LL * CHD;
#pragma unroll
  for (int h = 0; h < 2; ++h) {
    float inv = 1.f / Osum[h];
    int row = tW + h * 16 + lrow;
#pragma unroll
    for (int n = 0; n < 4; ++n) {
      unsigned d0 = pack2(Oa[h][n][0] * inv, Oa[h][n][1] * inv);
      unsigned d1 = pack2(Oa[h][n][2] * inv, Oa[h][n][3] * inv);
      *(uint2*)(ab + (size_t)row * CHD + n * 16 + quad * 4) = make_uint2(d0, d1);
    }
  }
}

// ---------------------------------------------------------------------------
// K4: proj GEMM (MFMA) + bias + fp32 residual, LDS double-buffered.
// Tile 128o x 64l, grid (8,4,16) = 512 blocks = 2/CU.  BK=64 == one head.
// ---------------------------------------------------------------------------
__global__ __launch_bounds__(256) void proj_mfma(const bf16_t* __restrict__ wp,
                                                 const bf16_t* __restrict__ at,
                                                 const float* __restrict__ projb,
                                                 const float* __restrict__ x,
                                                 float* __restrict__ out) {
  __shared__ bf16_t As[2][128 * 64];
  __shared__ bf16_t Bs[2][64 * 64];
  int tid = threadIdx.x;
  int wave = tid >> 6, lane = tid & 63;
  int lrow = lane & 15, quad = lane >> 4;
  int wm = wave >> 1, wn = wave & 1;
  int b = blockIdx.x;
  int oBase = blockIdx.y * 128, lBase = blockIdx.z * 64;
  int srow = lane >> 3;
  int sgOff = (((lane & 7) ^ srow) << 4);

  auto stage = [&](int buf, int ktile) {
    int kB = ktile * 64;
#pragma unroll
    for (int j = 0; j < 4; ++j) {               // As: 16 chunks, 4/wave
      int ci = wave * 4 + j;
      int R = ci * 8 + srow;
      gload_lds16((const char*)(wp + (size_t)(oBase + R) * CCH + kB) + sgOff,
                  (char*)&As[buf][0] + ci * 1024);
    }
#pragma unroll
    for (int j = 0; j < 2; ++j) {               // Bs: 8 chunks, 2/wave
      int ci = wave * 2 + j;
      int R = ci * 8 + srow;
      gload_lds16((const char*)(at + ((size_t)(b * NHEADS + ktile) * LL + lBase + R) * CHD) + sgOff,
                  (char*)&Bs[buf][0] + ci * 1024);
    }
  };

  stage(0, 0);
  __syncthreads();                         // drains prologue DMA

  f32x4 acc[4][2] = {};
  for (int ktile = 0; ktile < 8; ++ktile) {
    int cur = ktile & 1;
    if (ktile < 7) stage(cur ^ 1, ktile + 1);   // flies under this tile's compute
    const bf16_t* asrc = &As[cur][0];
    const bf16_t* bsrc = &Bs[cur][0];
#pragma unroll
    for (int kk = 0; kk < 2; ++kk) {
      int g = (kk * 4 + quad) ^ (lrow & 7);
      bf16x8 af[4], bfr[2];
#pragma unroll
      for (int m = 0; m < 4; ++m) {
        int r = wm * 64 + m * 16 + lrow;
        af[m] = *(const bf16x8*)(asrc + r * 64 + g * 8);
      }
#pragma unroll
      for (int n = 0; n < 2; ++n) {
        int r = wn * 32 + n * 16 + lrow;
        bfr[n] = *(const bf16x8*)(bsrc + r * 64 + g * 8);
      }
#pragma unroll
      for (int m = 0; m < 4; ++m)
#pragma unroll
        for (int n = 0; n < 2; ++n)
          acc[m][n] = __builtin_amdgcn_mfma_f32_16x16x32_bf16(af[m], bfr[n], acc[m][n], 0, 0, 0);
    }
    if (ktile < 7) __syncthreads();        // drains next-tile DMA + read-done sync
  }

  int oW = oBase + wm * 64;
  int lW = lBase + wn * 32;
#pragma unroll
  for (int m = 0; m < 4; ++m) {
#pragma unroll
    for (int i = 0; i < 4; ++i) {
      int o = oW + m * 16 + quad * 4 + i;
      float bb = projb[o];
#pragma unroll
      for (int n = 0; n < 2; ++n) {
        int l = lW + n * 16 + lrow;
        size_t off = ((size_t)(b * CCH + o)) * LL + l;
        out[off] = acc[m][n][i] + bb + x[off];
      }
    }
  }
}

// ---------------------------------------------------------------------------
extern "C" void kernel_launch(void* const* d_in, const int* in_sizes, int n_in,
                              void* d_out, int out_size, void* d_ws, size_t ws_size,
                              hipStream_t stream) {
  const float* x     = (const float*)d_in[0];
  const float* gsc   = (const float*)d_in[1];
  const float* gbi   = (const float*)d_in[2];
  const float* qkvw  = (const float*)d_in[3];
  const float* qkvb  = (const float*)d_in[4];
  const float* projw = (const float*)d_in[5];
  const float* projb = (const float*)d_in[6];
  float* out = (float*)d_out;

  char* ws = (char*)d_ws;
  bf16_t* wqb   = (bf16_t*)(ws + 4096);
  bf16_t* wpb   = (bf16_t*)(ws + 4096 + 1572864);
  bf16_t* xnT   = (bf16_t*)(ws + 2101248);
  bf16_t* qt    = (bf16_t*)(ws + 2101248 + 8388608);
  bf16_t* kt    = (bf16_t*)(ws + 2101248 + 2 * 8388608);
  bf16_t* vt    = (bf16_t*)(ws + 2101248 + 3 * 8388608);
  bf16_t* at    = (bf16_t*)(ws + 2101248 + 4 * 8388608);

  hipLaunchKernelGGL(prep_fused, dim3(1280), dim3(256), 0, stream,
                     qkvw, projw, wqb, wpb, x, gsc, gbi, xnT);
  hipLaunchKernelGGL(qkv_mfma, dim3(BATCH, 12, 8), dim3(256), 0, stream,
                     wqb, xnT, qkvb, qt, kt, vt);
  hipLaunchKernelGGL(attn_mfma, dim3(64, 8), dim3(256), 0, stream, qt, kt, vt, at);
  hipLaunchKernelGGL(proj_mfma, dim3(BATCH, 4, 16), dim3(256), 0, stream,
                     wpb, at, projb, x, out);
}

// Round 5
// 139.781 us; speedup vs baseline: 1.0313x; 1.0313x over previous
//
#include <hip/hip_runtime.h>
#include <math.h>

// (B,C,H,W)=(8,512,32,32), L=1024, 32 groups, 8 heads, ch=64
#define BATCH   8
#define CCH     512
#define LL      1024
#define NHEADS  8
#define CHD     64
#define EPSV    1e-5f
#define QSCALE  0.1803368801111204f   // 0.125 / ln(2): folded into q so S is in log2 units

typedef __bf16 bf16_t;
typedef bf16_t bf16x8 __attribute__((ext_vector_type(8)));
typedef bf16_t bf16x4 __attribute__((ext_vector_type(4)));
typedef float  f32x4  __attribute__((ext_vector_type(4)));

__device__ __forceinline__ bf16_t f2b(float f) {
  unsigned u = __float_as_uint(f);
  u += 0x7fff + ((u >> 16) & 1);               // RNE
  return __builtin_bit_cast(bf16_t, (unsigned short)(u >> 16));
}

__device__ __forceinline__ unsigned pack2(float lo, float hi) {
  unsigned a = (unsigned)__builtin_bit_cast(unsigned short, f2b(lo));
  unsigned b = (unsigned)__builtin_bit_cast(unsigned short, f2b(hi));
  return (b << 16) | a;
}

__device__ __forceinline__ void gload_lds16(const void* g, void* l) {
  __builtin_amdgcn_global_load_lds(
      (const __attribute__((address_space(1))) void*)g,
      (__attribute__((address_space(3))) void*)l, 16, 0, 0);
}

// ---------------------------------------------------------------------------
// K1: fused prep.  Blocks 0..1023: fp32->bf16 weight convert (qkv_w + proj_w).
// Blocks 1024..1279: GroupNorm stats+normalize+affine+transpose -> xnT bf16.
// ---------------------------------------------------------------------------
__global__ __launch_bounds__(256) void prep_fused(const float* __restrict__ qkvw,
                                                  const float* __restrict__ projw,
                                                  bf16_t* __restrict__ wqb,
                                                  bf16_t* __restrict__ wpb,
                                                  const float* __restrict__ x,
                                                  const float* __restrict__ gsc,
                                                  const float* __restrict__ gbi,
                                                  bf16_t* __restrict__ xnT) {
  int bid = blockIdx.x;
  int tid = threadIdx.x;
  if (bid < 1024) {
    int i = (bid * 256 + tid) * 4;
    const float* src;
    bf16_t* dst;
    int j;
    if (i < 1536 * 512) { src = qkvw; dst = wqb; j = i; }
    else                { src = projw; dst = wpb; j = i - 1536 * 512; }
    float4 v = *(const float4*)(src + j);
    bf16x4 o = {f2b(v.x), f2b(v.y), f2b(v.z), f2b(v.w)};
    *(bf16x4*)(dst + j) = o;
    return;
  }
  int lin = bid - 1024;
  int xcd = lin & 7, slot = lin >> 3;
  int b = slot & 7, jj = slot >> 3;
  int g = xcd * 4 + jj;
  const float4* x4 = (const float4*)(x + ((size_t)(b * 32 + g)) * 16 * LL);

  float s = 0.f, ss = 0.f;
  float4 v[16];
#pragma unroll
  for (int it = 0; it < 16; ++it) {
    float4 f = x4[it * 256 + tid];
    v[it] = f;
    s += f.x + f.y + f.z + f.w;
    ss += f.x * f.x + f.y * f.y + f.z * f.z + f.w * f.w;
  }
#pragma unroll
  for (int m = 1; m < 64; m <<= 1) { s += __shfl_xor(s, m); ss += __shfl_xor(ss, m); }
  __shared__ float rs_[4], rss[4];
  int wv = tid >> 6, ln = tid & 63;
  if (ln == 0) { rs_[wv] = s; rss[wv] = ss; }
  __syncthreads();
  s  = rs_[0] + rs_[1] + rs_[2] + rs_[3];
  ss = rss[0] + rss[1] + rss[2] + rss[3];
  float mean = s * (1.f / 16384.f);
  float var  = ss * (1.f / 16384.f) - mean * mean;
  float rstd = rsqrtf(var + EPSV);

  float sc[16], bi[16];
#pragma unroll
  for (int it = 0; it < 16; ++it) {
    sc[it] = gsc[g * 16 + it] * rstd;
    bi[it] = gbi[g * 16 + it] - mean * sc[it];
  }

#pragma unroll
  for (int j = 0; j < 4; ++j) {
    unsigned w[8];
#pragma unroll
    for (int k = 0; k < 8; ++k) {
      float a0 = (j == 0 ? v[2 * k].x : j == 1 ? v[2 * k].y : j == 2 ? v[2 * k].z : v[2 * k].w);
      float a1 = (j == 0 ? v[2 * k + 1].x : j == 1 ? v[2 * k + 1].y : j == 2 ? v[2 * k + 1].z : v[2 * k + 1].w);
      w[k] = pack2(a0 * sc[2 * k] + bi[2 * k], a1 * sc[2 * k + 1] + bi[2 * k + 1]);
    }
    int l = tid * 4 + j;
    bf16_t* dst = xnT + ((size_t)b * LL + l) * CCH + g * 16;
    *(uint4*)dst = make_uint4(w[0], w[1], w[2], w[3]);
    *(uint4*)(dst + 8) = make_uint4(w[4], w[5], w[6], w[7]);
  }
}

// ---------------------------------------------------------------------------
// K2: qkv GEMM (MFMA).  128x128 block tile, grid (8,12,8)=768 = 3/CU.
// Bs dbuf + counted s_waitcnt vmcnt(4) pipeline (T3/T4).  Wave tile 64x64.
// v epilogue: s-permuted packed uint2 stores (R3 proven; natural-order scalar
// stores in R4 regressed K2's store phase).
// ---------------------------------------------------------------------------
__global__ __launch_bounds__(256, 3) void qkv_mfma(const bf16_t* __restrict__ wq,
                                                   const bf16_t* __restrict__ xnT,
                                                   const float* __restrict__ qkvb,
                                                   bf16_t* __restrict__ qt,
                                                   bf16_t* __restrict__ kt,
                                                   bf16_t* __restrict__ vt) {
  __shared__ bf16_t As[128 * 64];       // single buffer (weights)
  __shared__ bf16_t Bs[2][128 * 64];    // double buffer (activations)
  int tid = threadIdx.x;
  int wave = tid >> 6, lane = tid & 63;
  int lrow = lane & 15, quad = lane >> 4;
  int wm = wave >> 1, wn = wave & 1;
  int b = blockIdx.x;
  int oBase = blockIdx.y * 128, lBase = blockIdx.z * 128;
  int srow = lane >> 3;
  int sgOff = (((lane & 7) ^ srow) << 4);

  // prologue: issue Bs[0] for ktile 0
#pragma unroll
  for (int j = 0; j < 4; ++j) {
    int ci = wave * 4 + j;
    int R = ci * 8 + srow;
    gload_lds16((const char*)(xnT + ((size_t)b * LL + lBase + R) * CCH) + sgOff,
                (char*)&Bs[0][0] + ci * 1024);
  }

  f32x4 acc[4][4] = {};
  for (int ktile = 0; ktile < 8; ++ktile) {
    int cur = ktile & 1;
    int kB = ktile * 64;
    __builtin_amdgcn_sched_barrier(0);
    __builtin_amdgcn_s_barrier();        // all waves done reading As / Bs[cur^1]
    __builtin_amdgcn_sched_barrier(0);
#pragma unroll
    for (int j = 0; j < 4; ++j) {        // As for THIS ktile (single buffer)
      int ci = wave * 4 + j;
      int R = ci * 8 + srow;
      gload_lds16((const char*)(wq + (size_t)(oBase + R) * CCH + kB) + sgOff,
                  (char*)As + ci * 1024);
    }
    if (ktile < 7) {
#pragma unroll
      for (int j = 0; j < 4; ++j) {      // Bs prefetch for NEXT ktile
        int ci = wave * 4 + j;
        int R = ci * 8 + srow;
        gload_lds16((const char*)(xnT + ((size_t)b * LL + lBase + R) * CCH + kB + 64) + sgOff,
                    (char*)&Bs[cur ^ 1][0] + ci * 1024);
      }
      asm volatile("s_waitcnt vmcnt(4)" ::: "memory");  // As_k + Bs_k retired; Bs_{k+1} flies
    } else {
      asm volatile("s_waitcnt vmcnt(0)" ::: "memory");
    }
    __builtin_amdgcn_s_barrier();        // staged data visible to all waves
    __builtin_amdgcn_sched_barrier(0);
    const bf16_t* bsrc = &Bs[cur][0];
#pragma unroll
    for (int kk = 0; kk < 2; ++kk) {
      int g = (kk * 4 + quad) ^ (lrow & 7);
      bf16x8 af[4], bfr[4];
#pragma unroll
      for (int m = 0; m < 4; ++m) {
        int r = wm * 64 + m * 16 + lrow;
        af[m] = *(const bf16x8*)(As + r * 64 + g * 8);
      }
#pragma unroll
      for (int n = 0; n < 4; ++n) {
        int r = wn * 64 + n * 16 + lrow;
        bfr[n] = *(const bf16x8*)(bsrc + r * 64 + g * 8);
      }
#pragma unroll
      for (int m = 0; m < 4; ++m)
#pragma unroll
        for (int n = 0; n < 4; ++n)
          acc[m][n] = __builtin_amdgcn_mfma_f32_16x16x32_bf16(af[m], bfr[n], acc[m][n], 0, 0, 0);
    }
  }

  int oW = oBase + wm * 64;
  int lW = lBase + wn * 64;
  int sec = oW >> 9;                            // wave-uniform
#pragma unroll
  for (int m = 0; m < 4; ++m) {
    int o4 = oW + m * 16 + quad * 4;
    float4 bb4 = *(const float4*)&qkvb[o4];
    int cc = o4 & 511;
    int head = cc >> 6, ch = cc & 63;
    int bh = b * NHEADS + head;
    if (sec == 0) {
#pragma unroll
      for (int n = 0; n < 4; ++n) {
        int l = lW + n * 16 + lrow;
        unsigned d0 = pack2((acc[m][n][0] + bb4.x) * QSCALE,
                            (acc[m][n][1] + bb4.y) * QSCALE);
        unsigned d1 = pack2((acc[m][n][2] + bb4.z) * QSCALE,
                            (acc[m][n][3] + bb4.w) * QSCALE);
        *(uint2*)(qt + ((size_t)bh * LL + l) * CHD + ch) = make_uint2(d0, d1);
      }
    } else if (sec == 1) {
#pragma unroll
      for (int n = 0; n < 4; ++n) {
        int l = lW + n * 16 + lrow;
        unsigned d0 = pack2(acc[m][n][0] + bb4.x, acc[m][n][1] + bb4.y);
        unsigned d1 = pack2(acc[m][n][2] + bb4.z, acc[m][n][3] + bb4.w);
        *(uint2*)(kt + ((size_t)bh * LL + l) * CHD + ch) = make_uint2(d0, d1);
      }
    } else {
      // v: within each 64-l chunk, position lrow*4+n holds l = n*16+lrow
      float bb[4] = {bb4.x, bb4.y, bb4.z, bb4.w};
#pragma unroll
      for (int i = 0; i < 4; ++i) {
        unsigned d0 = pack2(acc[m][0][i] + bb[i], acc[m][1][i] + bb[i]);
        unsigned d1 = pack2(acc[m][2][i] + bb[i], acc[m][3][i] + bb[i]);
        *(uint2*)(vt + ((size_t)bh * CHD + ch + i) * LL + lW + lrow * 4) =
            make_uint2(d0, d1);
      }
    }
  }
}

// ---------------------------------------------------------------------------
// K3: flash attention (MFMA), no-max softmax in log2 units.  R3 compute body
// (P through wave-private LDS, s-permuted to match vt; ones-MFMA row-sum).
// NEW (this round): TRIPLE-buffered K/V with 2-deep prefetch + counted
// s_waitcnt vmcnt(4) + raw s_barrier.  R3's __syncthreads drained the DMA to
// vmcnt(0) at EVERY step end, exposing the staging latency; now tile st+2 is
// issued at step st and only tile st+1's loads are retired at the barrier, so
// 4 loads always stay in flight and DMA gets ~2 compute phases to land.
// LDS 66 KB -> still 2 blocks/CU (what the 512-block grid needs).
// ---------------------------------------------------------------------------
__global__ __launch_bounds__(256) void attn_mfma(const bf16_t* __restrict__ qt,
                                                 const bf16_t* __restrict__ kt,
                                                 const bf16_t* __restrict__ vt,
                                                 bf16_t* __restrict__ at) {
  __shared__ bf16_t kbuf[3][64 * 64];
  __shared__ bf16_t vbuf[3][64 * 64];
  __shared__ bf16_t pb[8 * 16 * 72];            // per (wave,h) P tile, stride 72
  int tid = threadIdx.x, wave = tid >> 6, lane = tid & 63;
  int lrow = lane & 15, quad = lane >> 4;
  int bh = blockIdx.x;
  int tW = blockIdx.y * 128 + wave * 32;
  const bf16_t* qb = qt + (size_t)bh * LL * CHD;
  const bf16_t* kb = kt + (size_t)bh * LL * CHD;
  const bf16_t* vb = vt + (size_t)bh * CHD * LL;

  int srow = lane >> 3;
  int sgb = (((lane & 7) ^ srow) << 4);

  auto stageKV = [&](int buf, int tile) {
    int sBn = tile * 64;
#pragma unroll
    for (int j = 0; j < 2; ++j) {
      int c = wave * 2 + j;
      int R = c * 8 + srow;
      gload_lds16((const char*)(kb + (size_t)(sBn + R) * CHD) + sgb,
                  (char*)&kbuf[buf][0] + c * 1024);
      gload_lds16((const char*)(vb + (size_t)R * LL + sBn) + sgb,
                  (char*)&vbuf[buf][0] + c * 1024);
    }
  };

  bf16x8 qf[2][2];
#pragma unroll
  for (int h = 0; h < 2; ++h) {
    const bf16_t* qp = qb + (size_t)(tW + h * 16 + lrow) * CHD + quad * 8;
    qf[h][0] = *(const bf16x8*)qp;
    qf[h][1] = *(const bf16x8*)(qp + 32);
  }

  bf16x8 ones;
#pragma unroll
  for (int j = 0; j < 8; ++j) ones[j] = (bf16_t)1.0f;

  f32x4 Oa[2][4] = {};
  f32x4 Os[2] = {};

  stageKV(0, 0);
  stageKV(1, 1);
  __builtin_amdgcn_sched_barrier(0);
  asm volatile("s_waitcnt vmcnt(4)" ::: "memory");   // tile0 landed; tile1 flies
  __builtin_amdgcn_s_barrier();
  __builtin_amdgcn_sched_barrier(0);

  int swz0 = (quad ^ (lrow & 7)) * 8;
  int swz1 = ((quad + 4) ^ (lrow & 7)) * 8;

  for (int st = 0; st < 16; ++st) {
    int cur = st % 3;
    if (st + 2 < 16) stageKV((st + 2) % 3, st + 2);  // WAR-safe: buf read at st-1
    const bf16_t* kbase = &kbuf[cur][0];
    const bf16_t* vbase = &vbuf[cur][0];

    f32x4 S[2][4];
    __builtin_amdgcn_s_setprio(1);
#pragma unroll
    for (int ss = 0; ss < 4; ++ss) {
      int s = ss * 16 + lrow;
      bf16x8 k0 = *(const bf16x8*)(kbase + s * 64 + swz0);
      bf16x8 k1 = *(const bf16x8*)(kbase + s * 64 + swz1);
#pragma unroll
      for (int h = 0; h < 2; ++h) {
        f32x4 z = {0.f, 0.f, 0.f, 0.f};
        z = __builtin_amdgcn_mfma_f32_16x16x32_bf16(qf[h][0], k0, z, 0, 0, 0);
        S[h][ss] = __builtin_amdgcn_mfma_f32_16x16x32_bf16(qf[h][1], k1, z, 0, 0, 0);
      }
    }
    __builtin_amdgcn_s_setprio(0);

#pragma unroll
    for (int h = 0; h < 2; ++h) {
      bf16_t* pw = pb + (wave * 2 + h) * (16 * 72);
      float p[4][4];
#pragma unroll
      for (int ss = 0; ss < 4; ++ss)
#pragma unroll
        for (int i = 0; i < 4; ++i)
          p[ss][i] = __builtin_amdgcn_exp2f(S[h][ss][i]);
#pragma unroll
      for (int i = 0; i < 4; ++i) {
        unsigned d0 = __builtin_amdgcn_perm(__float_as_uint(p[1][i]),
                                            __float_as_uint(p[0][i]), 0x07060302u);
        unsigned d1 = __builtin_amdgcn_perm(__float_as_uint(p[3][i]),
                                            __float_as_uint(p[2][i]), 0x07060302u);
        uint2* dst = (uint2*)(pw + (quad * 4 + i) * 72 + lrow * 4);
        *dst = make_uint2(d0, d1);
      }
    }
    asm volatile("s_waitcnt lgkmcnt(0)" ::: "memory");   // wave-private P

    bf16x8 pf[2][2];
#pragma unroll
    for (int h = 0; h < 2; ++h) {
      const bf16_t* pw = pb + (wave * 2 + h) * (16 * 72);
      pf[h][0] = *(const bf16x8*)(pw + lrow * 72 + quad * 8);
      pf[h][1] = *(const bf16x8*)(pw + lrow * 72 + 32 + quad * 8);
    }

    __builtin_amdgcn_s_setprio(1);
#pragma unroll
    for (int n = 0; n < 4; ++n) {
      int r = (n * 16 + lrow) * 64;
      bf16x8 v0 = *(const bf16x8*)(vbase + r + swz0);
      bf16x8 v1 = *(const bf16x8*)(vbase + r + swz1);
#pragma unroll
      for (int h = 0; h < 2; ++h) {
        Oa[h][n] = __builtin_amdgcn_mfma_f32_16x16x32_bf16(pf[h][0], v0, Oa[h][n], 0, 0, 0);
        Oa[h][n] = __builtin_amdgcn_mfma_f32_16x16x32_bf16(pf[h][1], v1, Oa[h][n], 0, 0, 0);
      }
    }
#pragma unroll
    for (int h = 0; h < 2; ++h) {
      Os[h] = __builtin_amdgcn_mfma_f32_16x16x32_bf16(pf[h][0], ones, Os[h], 0, 0, 0);
      Os[h] = __builtin_amdgcn_mfma_f32_16x16x32_bf16(pf[h][1], ones, Os[h], 0, 0, 0);
    }
    __builtin_amdgcn_s_setprio(0);

    if (st < 15) {
      __builtin_amdgcn_sched_barrier(0);
      if (st + 2 < 16) {
        asm volatile("s_waitcnt vmcnt(4)" ::: "memory");  // tile st+1 landed
      } else {
        asm volatile("s_waitcnt vmcnt(0)" ::: "memory");
      }
      __builtin_amdgcn_s_barrier();
      __builtin_amdgcn_sched_barrier(0);
    }
  }

  bf16_t* ab = at + (size_t)bh * LL * CHD;
#pragma unroll
  for (int h = 0; h < 2; ++h) {
    float inv[4];
#pragma unroll
    for (int i = 0; i < 4; ++i) inv[i] = 1.f / Os[h][i];
#pragma unroll
    for (int n = 0; n < 4; ++n)
#pragma unroll
      for (int i = 0; i < 4; ++i)
        ab[(size_t)(tW + h * 16 + quad * 4 + i) * CHD + n * 16 + lrow] =
            f2b(Oa[h][n][i] * inv[i]);
  }
}

// ---------------------------------------------------------------------------
// K4: proj GEMM (MFMA) + bias + fp32 residual.
// NEW (this round): TRIPLE-buffered with 2-deep prefetch + counted vmcnt(6)
// + raw s_barrier (same rationale as K3: the dbuf __syncthreads drained the
// per-ktile DMA to 0 every tile).  Tile 128o x 64l, grid (8,4,16) = 512
// blocks = 2/CU; LDS 72 KB -> 2/CU preserved.  BK=64 == one head of at.
// ---------------------------------------------------------------------------
__global__ __launch_bounds__(256) void proj_mfma(const bf16_t* __restrict__ wp,
                                                 const bf16_t* __restrict__ at,
                                                 const float* __restrict__ projb,
                                                 const float* __restrict__ x,
                                                 float* __restrict__ out) {
  __shared__ bf16_t As[3][128 * 64];
  __shared__ bf16_t Bs[3][64 * 64];
  int tid = threadIdx.x;
  int wave = tid >> 6, lane = tid & 63;
  int lrow = lane & 15, quad = lane >> 4;
  int wm = wave >> 1, wn = wave & 1;
  int b = blockIdx.x;
  int oBase = blockIdx.y * 128, lBase = blockIdx.z * 64;
  int srow = lane >> 3;
  int sgOff = (((lane & 7) ^ srow) << 4);

  auto stage = [&](int buf, int ktile) {
    int kB = ktile * 64;
#pragma unroll
    for (int j = 0; j < 4; ++j) {               // As: 16 chunks, 4/wave
      int ci = wave * 4 + j;
      int R = ci * 8 + srow;
      gload_lds16((const char*)(wp + (size_t)(oBase + R) * CCH + kB) + sgOff,
                  (char*)&As[buf][0] + ci * 1024);
    }
#pragma unroll
    for (int j = 0; j < 2; ++j) {               // Bs: 8 chunks, 2/wave
      int ci = wave * 2 + j;
      int R = ci * 8 + srow;
      gload_lds16((const char*)(at + ((size_t)(b * NHEADS + ktile) * LL + lBase + R) * CHD) + sgOff,
                  (char*)&Bs[buf][0] + ci * 1024);
    }
  };

  stage(0, 0);
  stage(1, 1);
  __builtin_amdgcn_sched_barrier(0);
  asm volatile("s_waitcnt vmcnt(6)" ::: "memory");   // tile0 landed; tile1 flies
  __builtin_amdgcn_s_barrier();
  __builtin_amdgcn_sched_barrier(0);

  f32x4 acc[4][2] = {};
  for (int ktile = 0; ktile < 8; ++ktile) {
    int cur = ktile % 3;
    if (ktile + 2 < 8) stage((ktile + 2) % 3, ktile + 2);  // WAR-safe
    const bf16_t* asrc = &As[cur][0];
    const bf16_t* bsrc = &Bs[cur][0];
#pragma unroll
    for (int kk = 0; kk < 2; ++kk) {
      int g = (kk * 4 + quad) ^ (lrow & 7);
      bf16x8 af[4], bfr[2];
#pragma unroll
      for (int m = 0; m < 4; ++m) {
        int r = wm * 64 + m * 16 + lrow;
        af[m] = *(const bf16x8*)(asrc + r * 64 + g * 8);
      }
#pragma unroll
      for (int n = 0; n < 2; ++n) {
        int r = wn * 32 + n * 16 + lrow;
        bfr[n] = *(const bf16x8*)(bsrc + r * 64 + g * 8);
      }
#pragma unroll
      for (int m = 0; m < 4; ++m)
#pragma unroll
        for (int n = 0; n < 2; ++n)
          acc[m][n] = __builtin_amdgcn_mfma_f32_16x16x32_bf16(af[m], bfr[n], acc[m][n], 0, 0, 0);
    }
    if (ktile < 7) {
      __builtin_amdgcn_sched_barrier(0);
      if (ktile + 2 < 8) {
        asm volatile("s_waitcnt vmcnt(6)" ::: "memory");  // tile kt+1 landed
      } else {
        asm volatile("s_waitcnt vmcnt(0)" ::: "memory");
      }
      __builtin_amdgcn_s_barrier();
      __builtin_amdgcn_sched_barrier(0);
    }
  }

  int oW = oBase + wm * 64;
  int lW = lBase + wn * 32;
#pragma unroll
  for (int m = 0; m < 4; ++m) {
#pragma unroll
    for (int i = 0; i < 4; ++i) {
      int o = oW + m * 16 + quad * 4 + i;
      float bb = projb[o];
#pragma unroll
      for (int n = 0; n < 2; ++n) {
        int l = lW + n * 16 + lrow;
        size_t off = ((size_t)(b * CCH + o)) * LL + l;
        out[off] = acc[m][n][i] + bb + x[off];
      }
    }
  }
}

// ---------------------------------------------------------------------------
extern "C" void kernel_launch(void* const* d_in, const int* in_sizes, int n_in,
                              void* d_out, int out_size, void* d_ws, size_t ws_size,
                              hipStream_t stream) {
  const float* x     = (const float*)d_in[0];
  const float* gsc   = (const float*)d_in[1];
  const float* gbi   = (const float*)d_in[2];
  const float* qkvw  = (const float*)d_in[3];
  const float* qkvb  = (const float*)d_in[4];
  const float* projw = (const float*)d_in[5];
  const float* projb = (const float*)d_in[6];
  float* out = (float*)d_out;

  char* ws = (char*)d_ws;
  bf16_t* wqb   = (bf16_t*)(ws + 4096);
  bf16_t* wpb   = (bf16_t*)(ws + 4096 + 1572864);
  bf16_t* xnT   = (bf16_t*)(ws + 2101248);
  bf16_t* qt    = (bf16_t*)(ws + 2101248 + 8388608);
  bf16_t* kt    = (bf16_t*)(ws + 2101248 + 2 * 8388608);
  bf16_t* vt    = (bf16_t*)(ws + 2101248 + 3 * 8388608);
  bf16_t* at    = (bf16_t*)(ws + 2101248 + 4 * 8388608);

  hipLaunchKernelGGL(prep_fused, dim3(1280), dim3(256), 0, stream,
                     qkvw, projw, wqb, wpb, x, gsc, gbi, xnT);
  hipLaunchKernelGGL(qkv_mfma, dim3(BATCH, 12, 8), dim3(256), 0, stream,
                     wqb, xnT, qkvb, qt, kt, vt);
  hipLaunchKernelGGL(attn_mfma, dim3(64, 8), dim3(256), 0, stream, qt, kt, vt, at);
  hipLaunchKernelGGL(proj_mfma, dim3(BATCH, 4, 16), dim3(256), 0, stream,
                     wpb, at, projb, x, out);
}